// Round 5
// baseline (417.103 us; speedup 1.0000x reference)
//
#include <hip/hip_runtime.h>
#include <math.h>

#define Dd 256
#define Nn 4096
#define Bb 4
#define BQ 64       // q rows per attn block (4 waves; S-phase 16 q/wave)
#define BK 32       // kv rows per tile
#define SPLIT 4     // KV splits

typedef _Float16 f16;
typedef _Float16 half8 __attribute__((ext_vector_type(8)));
typedef _Float16 half4 __attribute__((ext_vector_type(4)));
typedef float f32x4 __attribute__((ext_vector_type(4)));

#define LOG2E 1.4426950408889634f

// DPP row_ror butterfly over 16-lane rows (VALU pipe, not LDS)
template <int CTRL>
__device__ __forceinline__ float dppf(float x) {
    int r = __builtin_amdgcn_update_dpp(0, __builtin_bit_cast(int, x),
                                        CTRL, 0xF, 0xF, false);
    return __builtin_bit_cast(float, r);
}
__device__ __forceinline__ float red16_max(float x) {
    x = fmaxf(x, dppf<0x128>(x));   // row_ror:8
    x = fmaxf(x, dppf<0x124>(x));   // row_ror:4
    x = fmaxf(x, dppf<0x122>(x));   // row_ror:2
    x = fmaxf(x, dppf<0x121>(x));   // row_ror:1
    return x;
}
__device__ __forceinline__ float red16_sum(float x) {
    x += dppf<0x128>(x); x += dppf<0x124>(x);
    x += dppf<0x122>(x); x += dppf<0x121>(x);
    return x;
}

// Async global->LDS DMA, 16 B per lane. dst must be wave-uniform; HW deposits
// lane i at dst + i*16B. (m97-verified width-16 path.)
__device__ __forceinline__ void dma16(const f16* src, f16* dst) {
    __builtin_amdgcn_global_load_lds(
        (const __attribute__((address_space(1))) void*)src,
        (__attribute__((address_space(3))) void*)dst, 16, 0, 0);
}

// LDS-only barrier: drains ds ops but NOT vmcnt, so in-flight K-DMA prefetch
// survives the mid-iteration sync (avoids the m97 vmcnt(0) drain).
__device__ __forceinline__ void barrier_lds_only() {
    __asm__ volatile("s_waitcnt lgkmcnt(0)\n\ts_barrier" ::: "memory");
}

// ---------------------------------------------------------------------------
// Kernel 0: W transpose+cast.  Wt[which][d'][d] = (f16) W[d][d']
// ---------------------------------------------------------------------------
__global__ __launch_bounds__(256) void wtrans(
    const float* __restrict__ Wq, const float* __restrict__ Wk,
    const float* __restrict__ Wv, f16* __restrict__ Wt)
{
    __shared__ float ld[64][65];
    const int which = blockIdx.y;
    const float* W = which == 0 ? Wq : (which == 1 ? Wk : Wv);
    const int tr = (blockIdx.x >> 2) * 64;
    const int tc = (blockIdx.x & 3) * 64;
    const int t = threadIdx.x;
    #pragma unroll
    for (int i = 0; i < 16; ++i) {
        int u = t + i * 256, r = u >> 6, c = u & 63;
        ld[r][c] = W[(size_t)(tr + r) * Dd + tc + c];
    }
    __syncthreads();
    f16* Wo = Wt + (size_t)which * Dd * Dd;
    #pragma unroll
    for (int i = 0; i < 16; ++i) {
        int u = t + i * 256, cp = u >> 6, rp = u & 63;
        Wo[(size_t)(tc + cp) * Dd + tr + rp] = (f16)ld[rp][cp];
    }
}

// ---------------------------------------------------------------------------
// Kernel 1: QKV projection via MFMA.
// K is written with a per-row granule-XOR swizzle (g' = g ^ (n&7), granules
// of 8 halfs) so attn can DMA rows linearly into LDS and still read
// B-fragments conflict-free without padding.
// ---------------------------------------------------------------------------
__global__ __launch_bounds__(256, 2) void qkv_mfma(
    const float* __restrict__ x, const f16* __restrict__ Wt,
    const float* __restrict__ bq, const float* __restrict__ bk,
    const float* __restrict__ bv,
    f16* __restrict__ Qh, f16* __restrict__ Kh, f16* __restrict__ Vth)
{
    __shared__ f16 xT[64][264];
    __shared__ f16 Wls[256][40];
    __shared__ float bs[256];
    const int t = threadIdx.x;
    const int wave = t >> 6, lane = t & 63, quad = lane >> 4, l15 = lane & 15;
    const int n0 = blockIdx.x * 64;
    const int b = blockIdx.y, which = blockIdx.z;
    const float* bias = which == 0 ? bq : (which == 1 ? bk : bv);
    bs[t] = bias[t];

    const float* xb = x + (size_t)b * Dd * Nn;
    #pragma unroll
    for (int i = 0; i < 16; ++i) {
        int u = t + i * 256, d = u >> 4, nq = (u & 15) * 4;
        float4 v4 = *(const float4*)&xb[(size_t)d * Nn + n0 + nq];
        xT[nq + 0][d] = (f16)v4.x; xT[nq + 1][d] = (f16)v4.y;
        xT[nq + 2][d] = (f16)v4.z; xT[nq + 3][d] = (f16)v4.w;
    }
    __syncthreads();

    half8 a[8];
    #pragma unroll
    for (int c = 0; c < 8; ++c)
        a[c] = *(const half8*)&xT[16 * wave + l15][c * 32 + quad * 8];

    f32x4 acc[16];
    #pragma unroll
    for (int dt = 0; dt < 16; ++dt) acc[dt] = (f32x4){0.f, 0.f, 0.f, 0.f};

    const f16* Wb = Wt + (size_t)which * Dd * Dd;
    for (int c = 0; c < 8; ++c) {
        __syncthreads();
        #pragma unroll
        for (int jj = 0; jj < 4; ++jj) {
            int u = t + jj * 256, dp = u >> 2, p = u & 3;
            *(half8*)&Wls[dp][p * 8] =
                *(const half8*)(Wb + (size_t)dp * Dd + c * 32 + p * 8);
        }
        __syncthreads();
        #pragma unroll
        for (int dt = 0; dt < 16; ++dt) {
            half8 bfr = *(const half8*)&Wls[dt * 16 + l15][quad * 8];
            acc[dt] = __builtin_amdgcn_mfma_f32_16x16x32_f16(a[c], bfr, acc[dt], 0, 0, 0);
        }
    }

    const int nrow = n0 + 16 * wave + quad * 4;
    if (which == 0) {
        f16* O = Qh + ((size_t)b * Nn + nrow) * Dd;
        #pragma unroll
        for (int dt = 0; dt < 16; ++dt) {
            int col = dt * 16 + l15;
            float bvv = bs[col];
            #pragma unroll
            for (int r = 0; r < 4; ++r)
                O[(size_t)r * Dd + col] = (f16)(acc[dt][r] + bvv);
        }
    } else if (which == 1) {
        // K with granule swizzle per row
        f16* O = Kh + ((size_t)b * Nn + nrow) * Dd;
        #pragma unroll
        for (int dt = 0; dt < 16; ++dt) {
            int col = dt * 16 + l15;
            float bvv = bs[col];
            int g = col >> 3, clow = col & 7;
            #pragma unroll
            for (int r = 0; r < 4; ++r) {
                int n = nrow + r;
                int cs = ((g ^ (n & 7)) << 3) | clow;
                O[(size_t)r * Dd + cs] = (f16)(acc[dt][r] + bvv);
            }
        }
    } else {
        f16* O = Vth + (size_t)b * Dd * Nn;
        #pragma unroll
        for (int dt = 0; dt < 16; ++dt) {
            int col = dt * 16 + l15;
            float bvv = bs[col];
            half4 o;
            #pragma unroll
            for (int r = 0; r < 4; ++r) o[r] = (f16)(acc[dt][r] + bvv);
            *(half4*)&O[(size_t)col * Nn + nrow] = o;
        }
    }
}

// ---------------------------------------------------------------------------
// Kernel 2: MFMA flash attention, split-KV, wave-split-D PV,
// double-buffered async K staging (global_load_lds), swizzled K layout.
// Per iter: [__syncthreads: drains prev DMA] -> issue DMA(next) -> V prefetch
// -> S MFMA -> softmax -> Ps publish -> [lds-only barrier] -> rescale+PV.
// LDS: 2*16KB K bufs + Ps 4.6KB + state = 37.5 KB -> 4 blocks/CU.
// ---------------------------------------------------------------------------
__global__ __launch_bounds__(256, 4) void attn_mfma(
    const f16* __restrict__ Qh, const f16* __restrict__ Kh,
    const f16* __restrict__ Vth, f16* __restrict__ Opart,
    float* __restrict__ mpart, float* __restrict__ lpart)
{
    __shared__ f16 Ksw[2][BK * 256];  // 32768 B, unpadded (DMA target)
    __shared__ f16 Ps[4][16][36];     //  4608 B  P[qb][q][kv]
    __shared__ float alpha_s[4][16];
    __shared__ float l_sh[4][16];

    const int t    = threadIdx.x;
    const int wave = t >> 6, lane = t & 63;
    const int quad = lane >> 4, l15 = lane & 15;

    const int flat = blockIdx.x;
    const int xcd  = flat & 7;
    const int jj   = flat >> 3;
    const int g    = xcd * 2 + (jj & 1);
    const int qi   = jj >> 1;
    const int b    = g >> 2;
    const int s    = g & 3;
    const int q0   = qi * BQ;
    const int qw   = q0 + wave * 16;
    const int kv0  = s * (Nn / SPLIT);

    // Q A-fragments, pre-scaled by log2(e)
    half8 qf[8];
    const f16* Qrow = Qh + ((size_t)b * Nn + qw + l15) * Dd + quad * 8;
    #pragma unroll
    for (int c = 0; c < 8; ++c) {
        qf[c] = *(const half8*)(Qrow + c * 32);
        qf[c] = qf[c] * (f16)LOG2E;
    }

    f32x4 acc[16];
    #pragma unroll
    for (int n = 0; n < 16; ++n) acc[n] = (f32x4){0.f, 0.f, 0.f, 0.f};
    f32x4 m4 = {-1e30f, -1e30f, -1e30f, -1e30f};
    f32x4 l4 = {0.f, 0.f, 0.f, 0.f};

    const f16* Kb   = Kh + (size_t)b * Nn * Dd;
    const f16* Vrow = Vth + (size_t)b * Dd * Nn
                    + (size_t)(wave * 64 + l15) * Nn + quad * 8;

    // Wave w DMAs rows [8w, 8w+8) of each tile: 4 instrs x (2 rows = 1 KB)
    auto dma_tile = [&](int k0, int bufi) {
        #pragma unroll
        for (int j2 = 0; j2 < 4; ++j2) {
            int instr = wave * 4 + j2;
            const f16* src = Kb + (size_t)(k0 + instr * 2) * Dd + lane * 8;
            dma16(src, &Ksw[bufi][instr * 512]);
        }
    };

    const int nIter = (Nn / SPLIT) / BK;   // 32
    dma_tile(kv0, 0);

    for (int it = 0; it < nIter; ++it) {
        const int k0 = kv0 + it * BK;
        __syncthreads();   // drains DMA for buf[it&1]; protects Ps/K reuse

        if (it + 1 < nIter) dma_tile(k0 + BK, (it + 1) & 1);

        // V B-fragments direct from global (consumed in PV, ~full-S cover)
        half8 vbf[4];
        #pragma unroll
        for (int dt = 0; dt < 4; ++dt)
            vbf[dt] = *(const half8*)(Vrow + (size_t)dt * 16 * Nn + k0);

        // S = Q K^T from swizzled LDS rows (granule ^ (row&7); note
        // (16+l15)&7 == l15&7 so one xor serves both row-blocks)
        const f16* Kt = &Ksw[it & 1][0];
        f32x4 S0 = {0.f, 0.f, 0.f, 0.f}, S1 = {0.f, 0.f, 0.f, 0.f};
        #pragma unroll
        for (int c = 0; c < 8; ++c) {
            int g0 = (((c * 4 + quad) ^ (l15 & 7)) << 3);
            half8 kb0 = *(const half8*)&Kt[l15 * 256 + g0];
            half8 kb1 = *(const half8*)&Kt[(16 + l15) * 256 + g0];
            S0 = __builtin_amdgcn_mfma_f32_16x16x32_f16(qf[c], kb0, S0, 0, 0, 0);
            S1 = __builtin_amdgcn_mfma_f32_16x16x32_f16(qf[c], kb1, S1, 0, 0, 0);
        }

        // Online softmax (exp2 domain), DPP reductions
        f32x4 tmax;
        tmax.x = red16_max(fmaxf(S0.x, S1.x));
        tmax.y = red16_max(fmaxf(S0.y, S1.y));
        tmax.z = red16_max(fmaxf(S0.z, S1.z));
        tmax.w = red16_max(fmaxf(S0.w, S1.w));
        f32x4 newm;
        newm.x = fmaxf(m4.x, tmax.x); newm.y = fmaxf(m4.y, tmax.y);
        newm.z = fmaxf(m4.z, tmax.z); newm.w = fmaxf(m4.w, tmax.w);
        f32x4 al;
        al.x = __builtin_amdgcn_exp2f(m4.x - newm.x);
        al.y = __builtin_amdgcn_exp2f(m4.y - newm.y);
        al.z = __builtin_amdgcn_exp2f(m4.z - newm.z);
        al.w = __builtin_amdgcn_exp2f(m4.w - newm.w);
        f32x4 P0, P1;
        P0.x = __builtin_amdgcn_exp2f(S0.x - newm.x);
        P0.y = __builtin_amdgcn_exp2f(S0.y - newm.y);
        P0.z = __builtin_amdgcn_exp2f(S0.z - newm.z);
        P0.w = __builtin_amdgcn_exp2f(S0.w - newm.w);
        P1.x = __builtin_amdgcn_exp2f(S1.x - newm.x);
        P1.y = __builtin_amdgcn_exp2f(S1.y - newm.y);
        P1.z = __builtin_amdgcn_exp2f(S1.z - newm.z);
        P1.w = __builtin_amdgcn_exp2f(S1.w - newm.w);
        f32x4 rsum;
        rsum.x = red16_sum(P0.x + P1.x);
        rsum.y = red16_sum(P0.y + P1.y);
        rsum.z = red16_sum(P0.z + P1.z);
        rsum.w = red16_sum(P0.w + P1.w);
        l4 = l4 * al + rsum;
        m4 = newm;

        // Publish P (f16) and alpha
        const int pr = quad * 4;
        Ps[wave][pr + 0][l15] = (f16)P0.x;
        Ps[wave][pr + 1][l15] = (f16)P0.y;
        Ps[wave][pr + 2][l15] = (f16)P0.z;
        Ps[wave][pr + 3][l15] = (f16)P0.w;
        Ps[wave][pr + 0][16 + l15] = (f16)P1.x;
        Ps[wave][pr + 1][16 + l15] = (f16)P1.y;
        Ps[wave][pr + 2][16 + l15] = (f16)P1.z;
        Ps[wave][pr + 3][16 + l15] = (f16)P1.w;
        if (l15 == 0) {
            float4 a4 = {al.x, al.y, al.z, al.w};
            *(float4*)&alpha_s[wave][pr] = a4;
        }
        barrier_lds_only();   // keeps K-DMA prefetch in flight

        // Rescale O by each q-block's alpha (skip when converged)
        float4 alq0 = *(const float4*)&alpha_s[0][pr];
        float4 alq1 = *(const float4*)&alpha_s[1][pr];
        float4 alq2 = *(const float4*)&alpha_s[2][pr];
        float4 alq3 = *(const float4*)&alpha_s[3][pr];
        int need = (alq0.x != 1.f) | (alq0.y != 1.f) | (alq0.z != 1.f) | (alq0.w != 1.f) |
                   (alq1.x != 1.f) | (alq1.y != 1.f) | (alq1.z != 1.f) | (alq1.w != 1.f) |
                   (alq2.x != 1.f) | (alq2.y != 1.f) | (alq2.z != 1.f) | (alq2.w != 1.f) |
                   (alq3.x != 1.f) | (alq3.y != 1.f) | (alq3.z != 1.f) | (alq3.w != 1.f);
        if (__any(need)) {
            f32x4 a0 = {alq0.x, alq0.y, alq0.z, alq0.w};
            f32x4 a1 = {alq1.x, alq1.y, alq1.z, alq1.w};
            f32x4 a2 = {alq2.x, alq2.y, alq2.z, alq2.w};
            f32x4 a3 = {alq3.x, alq3.y, alq3.z, alq3.w};
            #pragma unroll
            for (int dt = 0; dt < 4; ++dt) {
                acc[0 * 4 + dt] *= a0;
                acc[1 * 4 + dt] *= a1;
                acc[2 * 4 + dt] *= a2;
                acc[3 * 4 + dt] *= a3;
            }
        }

        // PV: 4 q-blocks x this wave's 4 d-tiles
        #pragma unroll
        for (int qb = 0; qb < 4; ++qb) {
            half4 alo = *(const half4*)&Ps[qb][l15][quad * 8];
            half4 ahi = *(const half4*)&Ps[qb][l15][quad * 8 + 4];
            half8 ap = __builtin_shufflevector(alo, ahi, 0, 1, 2, 3, 4, 5, 6, 7);
            #pragma unroll
            for (int dt = 0; dt < 4; ++dt)
                acc[qb * 4 + dt] =
                    __builtin_amdgcn_mfma_f32_16x16x32_f16(ap, vbf[dt], acc[qb * 4 + dt], 0, 0, 0);
        }
    }

    // Publish l, write m/l partials
    __syncthreads();
    if (l15 == 0) {
        const int pr = quad * 4;
        float4 lv = {l4.x, l4.y, l4.z, l4.w};
        *(float4*)&l_sh[wave][pr] = lv;
        float mv[4] = {m4.x, m4.y, m4.z, m4.w};
        float lvv[4] = {l4.x, l4.y, l4.z, l4.w};
        #pragma unroll
        for (int r = 0; r < 4; ++r) {
            int n = qw + pr + r;
            mpart[(size_t)(s * Bb + b) * Nn + n] = mv[r];
            lpart[(size_t)(s * Bb + b) * Nn + n] = lvv[r];
        }
    }
    __syncthreads();

    // Normalize + store partial O
    f16* Ob = Opart + (size_t)(s * Bb + b) * Dd * Nn;
    #pragma unroll
    for (int qb = 0; qb < 4; ++qb) {
        float4 lq = *(const float4*)&l_sh[qb][quad * 4];
        f32x4 inv = {1.f / lq.x, 1.f / lq.y, 1.f / lq.z, 1.f / lq.w};
        #pragma unroll
        for (int dt = 0; dt < 4; ++dt) {
            int d = wave * 64 + dt * 16 + l15;
            f32x4 o = acc[qb * 4 + dt] * inv;
            half4 oh;
            oh[0] = (f16)o.x; oh[1] = (f16)o.y; oh[2] = (f16)o.z; oh[3] = (f16)o.w;
            *(half4*)&Ob[(size_t)d * Nn + q0 + qb * 16 + quad * 4] = oh;
        }
    }
}

// ---------------------------------------------------------------------------
// Kernel 3: combine split partials (exp2 domain).
// ---------------------------------------------------------------------------
__global__ __launch_bounds__(256) void combine(
    const f16* __restrict__ Opart, const float* __restrict__ mpart,
    const float* __restrict__ lpart, float* __restrict__ out)
{
    const int t = threadIdx.x;
    const int n0 = (blockIdx.x * 256 + t) * 8;
    const int d = blockIdx.y, b = blockIdx.z;

    float m[SPLIT][8], l[SPLIT][8];
    #pragma unroll
    for (int s = 0; s < SPLIT; ++s) {
        size_t base = (size_t)(s * Bb + b) * Nn + n0;
        float4 a0 = *(const float4*)&mpart[base];
        float4 a1 = *(const float4*)&mpart[base + 4];
        float4 c0 = *(const float4*)&lpart[base];
        float4 c1 = *(const float4*)&lpart[base + 4];
        m[s][0]=a0.x; m[s][1]=a0.y; m[s][2]=a0.z; m[s][3]=a0.w;
        m[s][4]=a1.x; m[s][5]=a1.y; m[s][6]=a1.z; m[s][7]=a1.w;
        l[s][0]=c0.x; l[s][1]=c0.y; l[s][2]=c0.z; l[s][3]=c0.w;
        l[s][4]=c1.x; l[s][5]=c1.y; l[s][6]=c1.z; l[s][7]=c1.w;
    }
    float w[SPLIT][8];
    #pragma unroll
    for (int jx = 0; jx < 8; ++jx) {
        float M = m[0][jx];
        #pragma unroll
        for (int s = 1; s < SPLIT; ++s) M = fmaxf(M, m[s][jx]);
        float L = 0.f;
        #pragma unroll
        for (int s = 0; s < SPLIT; ++s) {
            float ws = l[s][jx] * __builtin_amdgcn_exp2f(m[s][jx] - M);
            w[s][jx] = ws; L += ws;
        }
        float invL = 1.f / L;
        #pragma unroll
        for (int s = 0; s < SPLIT; ++s) w[s][jx] *= invL;
    }

    float o[8];
    #pragma unroll
    for (int jx = 0; jx < 8; ++jx) o[jx] = 0.f;
    #pragma unroll
    for (int s = 0; s < SPLIT; ++s) {
        half8 h = *(const half8*)&Opart[((size_t)(s * Bb + b) * Dd + d) * Nn + n0];
        #pragma unroll
        for (int jx = 0; jx < 8; ++jx) o[jx] += w[s][jx] * (float)h[jx];
    }
    float* op = out + ((size_t)b * Dd + d) * Nn + n0;
    f32x4 o0 = {o[0], o[1], o[2], o[3]};
    f32x4 o1 = {o[4], o[5], o[6], o[7]};
    *(f32x4*)op = o0;
    *(f32x4*)(op + 4) = o1;
}

extern "C" void kernel_launch(void* const* d_in, const int* in_sizes, int n_in,
                              void* d_out, int out_size, void* d_ws, size_t ws_size,
                              hipStream_t stream) {
    const float* x  = (const float*)d_in[0];
    const float* Wq = (const float*)d_in[1];
    const float* bq = (const float*)d_in[2];
    const float* Wk = (const float*)d_in[3];
    const float* bk = (const float*)d_in[4];
    const float* Wv = (const float*)d_in[5];
    const float* bv = (const float*)d_in[6];
    float* out = (float*)d_out;

    f16* Qh    = (f16*)d_ws;
    f16* Kh    = Qh + (size_t)Bb * Nn * Dd;
    f16* Vth   = Kh + (size_t)Bb * Nn * Dd;
    f16* Wt    = Vth + (size_t)Bb * Nn * Dd;
    f16* Opart = Wt + (size_t)3 * Dd * Dd;
    float* mpart = (float*)(Opart + (size_t)SPLIT * Bb * Dd * Nn);
    float* lpart = mpart + (size_t)SPLIT * Bb * Nn;

    wtrans<<<dim3(16, 3), 256, 0, stream>>>(Wq, Wk, Wv, Wt);
    qkv_mfma<<<dim3(Nn / 64, Bb, 3), 256, 0, stream>>>(
        x, Wt, bq, bk, bv, Qh, Kh, Vth);
    attn_mfma<<<dim3((Nn / BQ) * Bb * SPLIT), 256, 0, stream>>>(
        Qh, Kh, Vth, Opart, mpart, lpart);
    combine<<<dim3(Nn / 2048, Dd, Bb), 256, 0, stream>>>(
        Opart, mpart, lpart, out);
}

// Round 6
// 406.902 us; speedup vs baseline: 1.0251x; 1.0251x over previous
//
#include <hip/hip_runtime.h>
#include <math.h>

#define Dd 256
#define Nn 4096
#define Bb 4
#define BQ 64       // q rows per attn block (4 waves; S-phase 16 q/wave)
#define BK 32       // kv rows per tile
#define SPLIT 4     // KV splits
#define NGROUP (Bb * SPLIT)          // 16 (b,s) groups
#define QTILES (Nn / BQ)             // 64 q-tiles per group

typedef _Float16 f16;
typedef _Float16 half8 __attribute__((ext_vector_type(8)));
typedef _Float16 half4 __attribute__((ext_vector_type(4)));
typedef float f32x4 __attribute__((ext_vector_type(4)));

#define LOG2E 1.4426950408889634f

// DPP row_ror butterfly over 16-lane rows (VALU pipe, not LDS)
template <int CTRL>
__device__ __forceinline__ float dppf(float x) {
    int r = __builtin_amdgcn_update_dpp(0, __builtin_bit_cast(int, x),
                                        CTRL, 0xF, 0xF, false);
    return __builtin_bit_cast(float, r);
}
__device__ __forceinline__ float red16_max(float x) {
    x = fmaxf(x, dppf<0x128>(x));   // row_ror:8
    x = fmaxf(x, dppf<0x124>(x));   // row_ror:4
    x = fmaxf(x, dppf<0x122>(x));   // row_ror:2
    x = fmaxf(x, dppf<0x121>(x));   // row_ror:1
    return x;
}
__device__ __forceinline__ float red16_sum(float x) {
    x += dppf<0x128>(x); x += dppf<0x124>(x);
    x += dppf<0x122>(x); x += dppf<0x121>(x);
    return x;
}

// Physical XCD id (hwreg 20 = HW_REG_XCC_ID on gfx94x/gfx950). Numeric form
// always assembles; if the id were wrong we'd only lose locality, not
// correctness (the work-claim loop is valid for any value).
__device__ __forceinline__ int xcc_id() {
    int x;
    asm volatile("s_getreg_b32 %0, hwreg(20, 0, 32)" : "=s"(x));
    return x & 7;
}

// ---------------------------------------------------------------------------
// Kernel 0: W transpose+cast.  Wt[which][d'][d] = (f16) W[d][d']
// ---------------------------------------------------------------------------
__global__ __launch_bounds__(256) void wtrans(
    const float* __restrict__ Wq, const float* __restrict__ Wk,
    const float* __restrict__ Wv, f16* __restrict__ Wt)
{
    __shared__ float ld[64][65];
    const int which = blockIdx.y;
    const float* W = which == 0 ? Wq : (which == 1 ? Wk : Wv);
    const int tr = (blockIdx.x >> 2) * 64;
    const int tc = (blockIdx.x & 3) * 64;
    const int t = threadIdx.x;
    #pragma unroll
    for (int i = 0; i < 16; ++i) {
        int u = t + i * 256, r = u >> 6, c = u & 63;
        ld[r][c] = W[(size_t)(tr + r) * Dd + tc + c];
    }
    __syncthreads();
    f16* Wo = Wt + (size_t)which * Dd * Dd;
    #pragma unroll
    for (int i = 0; i < 16; ++i) {
        int u = t + i * 256, cp = u >> 6, rp = u & 63;
        Wo[(size_t)(tc + cp) * Dd + tr + rp] = (f16)ld[rp][cp];
    }
}

// ---------------------------------------------------------------------------
// Kernel 1: QKV projection via MFMA (R3 structure, plain K layout).
// ---------------------------------------------------------------------------
__global__ __launch_bounds__(256, 2) void qkv_mfma(
    const float* __restrict__ x, const f16* __restrict__ Wt,
    const float* __restrict__ bq, const float* __restrict__ bk,
    const float* __restrict__ bv,
    f16* __restrict__ Qh, f16* __restrict__ Kh, f16* __restrict__ Vth)
{
    __shared__ f16 xT[64][264];
    __shared__ f16 Wls[256][40];
    __shared__ float bs[256];
    const int t = threadIdx.x;
    const int wave = t >> 6, lane = t & 63, quad = lane >> 4, l15 = lane & 15;
    const int n0 = blockIdx.x * 64;
    const int b = blockIdx.y, which = blockIdx.z;
    const float* bias = which == 0 ? bq : (which == 1 ? bk : bv);
    bs[t] = bias[t];

    const float* xb = x + (size_t)b * Dd * Nn;
    #pragma unroll
    for (int i = 0; i < 16; ++i) {
        int u = t + i * 256, d = u >> 4, nq = (u & 15) * 4;
        float4 v4 = *(const float4*)&xb[(size_t)d * Nn + n0 + nq];
        xT[nq + 0][d] = (f16)v4.x; xT[nq + 1][d] = (f16)v4.y;
        xT[nq + 2][d] = (f16)v4.z; xT[nq + 3][d] = (f16)v4.w;
    }
    __syncthreads();

    half8 a[8];
    #pragma unroll
    for (int c = 0; c < 8; ++c)
        a[c] = *(const half8*)&xT[16 * wave + l15][c * 32 + quad * 8];

    f32x4 acc[16];
    #pragma unroll
    for (int dt = 0; dt < 16; ++dt) acc[dt] = (f32x4){0.f, 0.f, 0.f, 0.f};

    const f16* Wb = Wt + (size_t)which * Dd * Dd;
    for (int c = 0; c < 8; ++c) {
        __syncthreads();
        #pragma unroll
        for (int jj = 0; jj < 4; ++jj) {
            int u = t + jj * 256, dp = u >> 2, p = u & 3;
            *(half8*)&Wls[dp][p * 8] =
                *(const half8*)(Wb + (size_t)dp * Dd + c * 32 + p * 8);
        }
        __syncthreads();
        #pragma unroll
        for (int dt = 0; dt < 16; ++dt) {
            half8 bfr = *(const half8*)&Wls[dt * 16 + l15][quad * 8];
            acc[dt] = __builtin_amdgcn_mfma_f32_16x16x32_f16(a[c], bfr, acc[dt], 0, 0, 0);
        }
    }

    const int nrow = n0 + 16 * wave + quad * 4;
    if (which < 2) {
        f16* O = (which == 0 ? Qh : Kh) + ((size_t)b * Nn + nrow) * Dd;
        #pragma unroll
        for (int dt = 0; dt < 16; ++dt) {
            int col = dt * 16 + l15;
            float bvv = bs[col];
            #pragma unroll
            for (int r = 0; r < 4; ++r)
                O[(size_t)r * Dd + col] = (f16)(acc[dt][r] + bvv);
        }
    } else {
        f16* O = Vth + (size_t)b * Dd * Nn;
        #pragma unroll
        for (int dt = 0; dt < 16; ++dt) {
            int col = dt * 16 + l15;
            float bvv = bs[col];
            half4 o;
            #pragma unroll
            for (int r = 0; r < 4; ++r) o[r] = (f16)(acc[dt][r] + bvv);
            *(half4*)&O[(size_t)col * Nn + nrow] = o;
        }
    }
}

// ---------------------------------------------------------------------------
// Kernel 2: MFMA flash attention, split-KV, wave-split-D PV,
// XCD-AFFINE work claiming: each block reads its physical XCC_ID and claims
// a (group, q-tile) item from per-group atomic counters, preferring the two
// groups pinned to its own XCD -> per-XCD KV working set 2 MB < 4 MB L2.
// Scan rotation over all 16 groups guarantees exactly-once coverage.
// ---------------------------------------------------------------------------
__global__ __launch_bounds__(256, 4) void attn_mfma(
    const f16* __restrict__ Qh, const f16* __restrict__ Kh,
    const f16* __restrict__ Vth, f16* __restrict__ Opart,
    float* __restrict__ mpart, float* __restrict__ lpart,
    int* __restrict__ cnt)
{
    __shared__ f16 Ks[BK][264];       // 16896 B  K[kv][d]
    __shared__ f16 Ps[4][16][36];     //  4608 B  P[qb][q][kv]
    __shared__ float alpha_s[4][16];
    __shared__ float l_sh[4][16];
    __shared__ int work;

    const int t    = threadIdx.x;
    const int wave = t >> 6, lane = t & 63;
    const int quad = lane >> 4, l15 = lane & 15;

    // --- claim a work item with XCD affinity ---
    if (t == 0) {
        int xcd = xcc_id();
        int sel = -1;
        for (int a = 0; a < NGROUP && sel < 0; ++a) {
            int gg = (2 * xcd + a) & (NGROUP - 1);
            int r = atomicAdd(&cnt[gg], 1);
            if (r < QTILES) sel = (gg << 6) | r;
        }
        work = sel;   // guaranteed >= 0 (1024 slots, 1024 blocks)
    }
    __syncthreads();
    const int g  = work >> 6;
    const int qi = work & 63;
    const int b  = g >> 2;
    const int s  = g & 3;
    const int q0 = qi * BQ;
    const int qw = q0 + wave * 16;
    const int kv0 = s * (Nn / SPLIT);

    // Q A-fragments, pre-scaled by log2(e)
    half8 qf[8];
    const f16* Qrow = Qh + ((size_t)b * Nn + qw + l15) * Dd + quad * 8;
    #pragma unroll
    for (int c = 0; c < 8; ++c) {
        qf[c] = *(const half8*)(Qrow + c * 32);
        qf[c] = qf[c] * (f16)LOG2E;
    }

    f32x4 acc[16];
    #pragma unroll
    for (int n = 0; n < 16; ++n) acc[n] = (f32x4){0.f, 0.f, 0.f, 0.f};
    f32x4 m4 = {-1e30f, -1e30f, -1e30f, -1e30f};
    f32x4 l4 = {0.f, 0.f, 0.f, 0.f};

    const f16* Kb   = Kh + (size_t)b * Nn * Dd;
    const f16* Vrow = Vth + (size_t)b * Dd * Nn
                    + (size_t)(wave * 64 + l15) * Nn + quad * 8;

    for (int k0 = kv0; k0 < kv0 + Nn / SPLIT; k0 += BK) {
        __syncthreads();   // prior-iter Ks/Ps readers done

        // Stage K tile (VGPR roundtrip, coalesced 16B lanes)
        #pragma unroll
        for (int i = 0; i < 4; ++i) {
            int u = t + i * 256;
            int r = u >> 5, c = u & 31;
            *(half8*)&Ks[r][c * 8] =
                *(const half8*)(Kb + (size_t)(k0 + r) * Dd + c * 8);
        }
        __syncthreads();

        // V B-fragments direct from global (L2-resident after affinity fix)
        half8 vbf[4];
        #pragma unroll
        for (int dt = 0; dt < 4; ++dt)
            vbf[dt] = *(const half8*)(Vrow + (size_t)dt * 16 * Nn + k0);

        // S = Q K^T (log2 domain), two 16x16 blocks
        f32x4 S0 = {0.f, 0.f, 0.f, 0.f}, S1 = {0.f, 0.f, 0.f, 0.f};
        #pragma unroll
        for (int c = 0; c < 8; ++c) {
            half8 kb0 = *(const half8*)&Ks[l15][c * 32 + quad * 8];
            half8 kb1 = *(const half8*)&Ks[16 + l15][c * 32 + quad * 8];
            S0 = __builtin_amdgcn_mfma_f32_16x16x32_f16(qf[c], kb0, S0, 0, 0, 0);
            S1 = __builtin_amdgcn_mfma_f32_16x16x32_f16(qf[c], kb1, S1, 0, 0, 0);
        }

        // Online softmax (exp2 domain), DPP reductions
        f32x4 tmax;
        tmax.x = red16_max(fmaxf(S0.x, S1.x));
        tmax.y = red16_max(fmaxf(S0.y, S1.y));
        tmax.z = red16_max(fmaxf(S0.z, S1.z));
        tmax.w = red16_max(fmaxf(S0.w, S1.w));
        f32x4 newm;
        newm.x = fmaxf(m4.x, tmax.x); newm.y = fmaxf(m4.y, tmax.y);
        newm.z = fmaxf(m4.z, tmax.z); newm.w = fmaxf(m4.w, tmax.w);
        f32x4 al;
        al.x = __builtin_amdgcn_exp2f(m4.x - newm.x);
        al.y = __builtin_amdgcn_exp2f(m4.y - newm.y);
        al.z = __builtin_amdgcn_exp2f(m4.z - newm.z);
        al.w = __builtin_amdgcn_exp2f(m4.w - newm.w);
        f32x4 P0, P1;
        P0.x = __builtin_amdgcn_exp2f(S0.x - newm.x);
        P0.y = __builtin_amdgcn_exp2f(S0.y - newm.y);
        P0.z = __builtin_amdgcn_exp2f(S0.z - newm.z);
        P0.w = __builtin_amdgcn_exp2f(S0.w - newm.w);
        P1.x = __builtin_amdgcn_exp2f(S1.x - newm.x);
        P1.y = __builtin_amdgcn_exp2f(S1.y - newm.y);
        P1.z = __builtin_amdgcn_exp2f(S1.z - newm.z);
        P1.w = __builtin_amdgcn_exp2f(S1.w - newm.w);
        f32x4 rsum;
        rsum.x = red16_sum(P0.x + P1.x);
        rsum.y = red16_sum(P0.y + P1.y);
        rsum.z = red16_sum(P0.z + P1.z);
        rsum.w = red16_sum(P0.w + P1.w);
        l4 = l4 * al + rsum;
        m4 = newm;

        // Publish P (f16) and alpha
        const int pr = quad * 4;
        Ps[wave][pr + 0][l15] = (f16)P0.x;
        Ps[wave][pr + 1][l15] = (f16)P0.y;
        Ps[wave][pr + 2][l15] = (f16)P0.z;
        Ps[wave][pr + 3][l15] = (f16)P0.w;
        Ps[wave][pr + 0][16 + l15] = (f16)P1.x;
        Ps[wave][pr + 1][16 + l15] = (f16)P1.y;
        Ps[wave][pr + 2][16 + l15] = (f16)P1.z;
        Ps[wave][pr + 3][16 + l15] = (f16)P1.w;
        if (l15 == 0) {
            float4 a4 = {al.x, al.y, al.z, al.w};
            *(float4*)&alpha_s[wave][pr] = a4;
        }
        __syncthreads();

        // Rescale O by each q-block's alpha (skip when converged)
        float4 alq0 = *(const float4*)&alpha_s[0][pr];
        float4 alq1 = *(const float4*)&alpha_s[1][pr];
        float4 alq2 = *(const float4*)&alpha_s[2][pr];
        float4 alq3 = *(const float4*)&alpha_s[3][pr];
        int need = (alq0.x != 1.f) | (alq0.y != 1.f) | (alq0.z != 1.f) | (alq0.w != 1.f) |
                   (alq1.x != 1.f) | (alq1.y != 1.f) | (alq1.z != 1.f) | (alq1.w != 1.f) |
                   (alq2.x != 1.f) | (alq2.y != 1.f) | (alq2.z != 1.f) | (alq2.w != 1.f) |
                   (alq3.x != 1.f) | (alq3.y != 1.f) | (alq3.z != 1.f) | (alq3.w != 1.f);
        if (__any(need)) {
            f32x4 a0 = {alq0.x, alq0.y, alq0.z, alq0.w};
            f32x4 a1 = {alq1.x, alq1.y, alq1.z, alq1.w};
            f32x4 a2 = {alq2.x, alq2.y, alq2.z, alq2.w};
            f32x4 a3 = {alq3.x, alq3.y, alq3.z, alq3.w};
            #pragma unroll
            for (int dt = 0; dt < 4; ++dt) {
                acc[0 * 4 + dt] *= a0;
                acc[1 * 4 + dt] *= a1;
                acc[2 * 4 + dt] *= a2;
                acc[3 * 4 + dt] *= a3;
            }
        }

        // PV: 4 q-blocks x this wave's 4 d-tiles
        #pragma unroll
        for (int qb = 0; qb < 4; ++qb) {
            half4 alo = *(const half4*)&Ps[qb][l15][quad * 8];
            half4 ahi = *(const half4*)&Ps[qb][l15][quad * 8 + 4];
            half8 ap = __builtin_shufflevector(alo, ahi, 0, 1, 2, 3, 4, 5, 6, 7);
            #pragma unroll
            for (int dt = 0; dt < 4; ++dt)
                acc[qb * 4 + dt] =
                    __builtin_amdgcn_mfma_f32_16x16x32_f16(ap, vbf[dt], acc[qb * 4 + dt], 0, 0, 0);
        }
    }

    // Publish l, write m/l partials
    __syncthreads();
    if (l15 == 0) {
        const int pr = quad * 4;
        float4 lv = {l4.x, l4.y, l4.z, l4.w};
        *(float4*)&l_sh[wave][pr] = lv;
        float mv[4] = {m4.x, m4.y, m4.z, m4.w};
        float lvv[4] = {l4.x, l4.y, l4.z, l4.w};
        #pragma unroll
        for (int r = 0; r < 4; ++r) {
            int n = qw + pr + r;
            mpart[(size_t)(s * Bb + b) * Nn + n] = mv[r];
            lpart[(size_t)(s * Bb + b) * Nn + n] = lvv[r];
        }
    }
    __syncthreads();

    // Normalize + store partial O
    f16* Ob = Opart + (size_t)(s * Bb + b) * Dd * Nn;
    #pragma unroll
    for (int qb = 0; qb < 4; ++qb) {
        float4 lq = *(const float4*)&l_sh[qb][quad * 4];
        f32x4 inv = {1.f / lq.x, 1.f / lq.y, 1.f / lq.z, 1.f / lq.w};
        #pragma unroll
        for (int dt = 0; dt < 4; ++dt) {
            int d = wave * 64 + dt * 16 + l15;
            f32x4 o = acc[qb * 4 + dt] * inv;
            half4 oh;
            oh[0] = (f16)o.x; oh[1] = (f16)o.y; oh[2] = (f16)o.z; oh[3] = (f16)o.w;
            *(half4*)&Ob[(size_t)d * Nn + q0 + qb * 16 + quad * 4] = oh;
        }
    }
}

// ---------------------------------------------------------------------------
// Kernel 3: combine split partials (exp2 domain).
// ---------------------------------------------------------------------------
__global__ __launch_bounds__(256) void combine(
    const f16* __restrict__ Opart, const float* __restrict__ mpart,
    const float* __restrict__ lpart, float* __restrict__ out)
{
    const int t = threadIdx.x;
    const int n0 = (blockIdx.x * 256 + t) * 8;
    const int d = blockIdx.y, b = blockIdx.z;

    float m[SPLIT][8], l[SPLIT][8];
    #pragma unroll
    for (int s = 0; s < SPLIT; ++s) {
        size_t base = (size_t)(s * Bb + b) * Nn + n0;
        float4 a0 = *(const float4*)&mpart[base];
        float4 a1 = *(const float4*)&mpart[base + 4];
        float4 c0 = *(const float4*)&lpart[base];
        float4 c1 = *(const float4*)&lpart[base + 4];
        m[s][0]=a0.x; m[s][1]=a0.y; m[s][2]=a0.z; m[s][3]=a0.w;
        m[s][4]=a1.x; m[s][5]=a1.y; m[s][6]=a1.z; m[s][7]=a1.w;
        l[s][0]=c0.x; l[s][1]=c0.y; l[s][2]=c0.z; l[s][3]=c0.w;
        l[s][4]=c1.x; l[s][5]=c1.y; l[s][6]=c1.z; l[s][7]=c1.w;
    }
    float w[SPLIT][8];
    #pragma unroll
    for (int jx = 0; jx < 8; ++jx) {
        float M = m[0][jx];
        #pragma unroll
        for (int s = 1; s < SPLIT; ++s) M = fmaxf(M, m[s][jx]);
        float L = 0.f;
        #pragma unroll
        for (int s = 0; s < SPLIT; ++s) {
            float ws = l[s][jx] * __builtin_amdgcn_exp2f(m[s][jx] - M);
            w[s][jx] = ws; L += ws;
        }
        float invL = 1.f / L;
        #pragma unroll
        for (int s = 0; s < SPLIT; ++s) w[s][jx] *= invL;
    }

    float o[8];
    #pragma unroll
    for (int jx = 0; jx < 8; ++jx) o[jx] = 0.f;
    #pragma unroll
    for (int s = 0; s < SPLIT; ++s) {
        half8 h = *(const half8*)&Opart[((size_t)(s * Bb + b) * Dd + d) * Nn + n0];
        #pragma unroll
        for (int jx = 0; jx < 8; ++jx) o[jx] += w[s][jx] * (float)h[jx];
    }
    float* op = out + ((size_t)b * Dd + d) * Nn + n0;
    f32x4 o0 = {o[0], o[1], o[2], o[3]};
    f32x4 o1 = {o[4], o[5], o[6], o[7]};
    *(f32x4*)op = o0;
    *(f32x4*)(op + 4) = o1;
}

extern "C" void kernel_launch(void* const* d_in, const int* in_sizes, int n_in,
                              void* d_out, int out_size, void* d_ws, size_t ws_size,
                              hipStream_t stream) {
    const float* x  = (const float*)d_in[0];
    const float* Wq = (const float*)d_in[1];
    const float* bq = (const float*)d_in[2];
    const float* Wk = (const float*)d_in[3];
    const float* bk = (const float*)d_in[4];
    const float* Wv = (const float*)d_in[5];
    const float* bv = (const float*)d_in[6];
    float* out = (float*)d_out;

    f16* Qh    = (f16*)d_ws;
    f16* Kh    = Qh + (size_t)Bb * Nn * Dd;
    f16* Vth   = Kh + (size_t)Bb * Nn * Dd;
    f16* Wt    = Vth + (size_t)Bb * Nn * Dd;
    f16* Opart = Wt + (size_t)3 * Dd * Dd;
    float* mpart = (float*)(Opart + (size_t)SPLIT * Bb * Dd * Nn);
    float* lpart = mpart + (size_t)SPLIT * Bb * Nn;
    int*   cnt   = (int*)(lpart + (size_t)SPLIT * Bb * Nn);

    hipMemsetAsync(cnt, 0, NGROUP * sizeof(int), stream);
    wtrans<<<dim3(16, 3), 256, 0, stream>>>(Wq, Wk, Wv, Wt);
    qkv_mfma<<<dim3(Nn / 64, Bb, 3), 256, 0, stream>>>(
        x, Wt, bq, bk, bv, Qh, Kh, Vth);
    attn_mfma<<<dim3((Nn / BQ) * Bb * SPLIT), 256, 0, stream>>>(
        Qh, Kh, Vth, Opart, mpart, lpart, cnt);
    combine<<<dim3(Nn / 2048, Dd, Bb), 256, 0, stream>>>(
        Opart, mpart, lpart, out);
}

// Round 7
// 298.419 us; speedup vs baseline: 1.3977x; 1.3635x over previous
//
#include <hip/hip_runtime.h>
#include <math.h>

#define Dd 256
#define Nn 4096
#define Bb 4
#define BQ 128      // q rows per attn block (8 waves x 16 in S phase)
#define BK 32       // kv rows per sub-tile (paired: 64 per outer iter)
#define SPLIT 4     // KV splits

typedef _Float16 f16;
typedef _Float16 half8 __attribute__((ext_vector_type(8)));
typedef _Float16 half4 __attribute__((ext_vector_type(4)));
typedef float f32x4 __attribute__((ext_vector_type(4)));

#define LOG2E 1.4426950408889634f

// DPP row_ror butterfly over 16-lane rows (VALU pipe, not LDS)
template <int CTRL>
__device__ __forceinline__ float dppf(float x) {
    int r = __builtin_amdgcn_update_dpp(0, __builtin_bit_cast(int, x),
                                        CTRL, 0xF, 0xF, false);
    return __builtin_bit_cast(float, r);
}
__device__ __forceinline__ float red16_max(float x) {
    x = fmaxf(x, dppf<0x128>(x));
    x = fmaxf(x, dppf<0x124>(x));
    x = fmaxf(x, dppf<0x122>(x));
    x = fmaxf(x, dppf<0x121>(x));
    return x;
}
__device__ __forceinline__ float red16_sum(float x) {
    x += dppf<0x128>(x); x += dppf<0x124>(x);
    x += dppf<0x122>(x); x += dppf<0x121>(x);
    return x;
}

// ---------------------------------------------------------------------------
// Kernel 0: W transpose+cast.  Wt[which][d'][d] = (f16) W[d][d']
// ---------------------------------------------------------------------------
__global__ __launch_bounds__(256) void wtrans(
    const float* __restrict__ Wq, const float* __restrict__ Wk,
    const float* __restrict__ Wv, f16* __restrict__ Wt)
{
    __shared__ float ld[64][65];
    const int which = blockIdx.y;
    const float* W = which == 0 ? Wq : (which == 1 ? Wk : Wv);
    const int tr = (blockIdx.x >> 2) * 64;
    const int tc = (blockIdx.x & 3) * 64;
    const int t = threadIdx.x;
    #pragma unroll
    for (int i = 0; i < 16; ++i) {
        int u = t + i * 256, r = u >> 6, c = u & 63;
        ld[r][c] = W[(size_t)(tr + r) * Dd + tc + c];
    }
    __syncthreads();
    f16* Wo = Wt + (size_t)which * Dd * Dd;
    #pragma unroll
    for (int i = 0; i < 16; ++i) {
        int u = t + i * 256, cp = u >> 6, rp = u & 63;
        Wo[(size_t)(tc + cp) * Dd + tr + rp] = (f16)ld[rp][cp];
    }
}

// ---------------------------------------------------------------------------
// Kernel 1: QKV projection via MFMA (unchanged).
// ---------------------------------------------------------------------------
__global__ __launch_bounds__(256, 2) void qkv_mfma(
    const float* __restrict__ x, const f16* __restrict__ Wt,
    const float* __restrict__ bq, const float* __restrict__ bk,
    const float* __restrict__ bv,
    f16* __restrict__ Qh, f16* __restrict__ Kh, f16* __restrict__ Vth)
{
    __shared__ f16 xT[64][264];
    __shared__ f16 Wls[256][40];
    __shared__ float bs[256];
    const int t = threadIdx.x;
    const int wave = t >> 6, lane = t & 63, quad = lane >> 4, l15 = lane & 15;
    const int n0 = blockIdx.x * 64;
    const int b = blockIdx.y, which = blockIdx.z;
    const float* bias = which == 0 ? bq : (which == 1 ? bk : bv);
    bs[t] = bias[t];

    const float* xb = x + (size_t)b * Dd * Nn;
    #pragma unroll
    for (int i = 0; i < 16; ++i) {
        int u = t + i * 256, d = u >> 4, nq = (u & 15) * 4;
        float4 v4 = *(const float4*)&xb[(size_t)d * Nn + n0 + nq];
        xT[nq + 0][d] = (f16)v4.x; xT[nq + 1][d] = (f16)v4.y;
        xT[nq + 2][d] = (f16)v4.z; xT[nq + 3][d] = (f16)v4.w;
    }
    __syncthreads();

    half8 a[8];
    #pragma unroll
    for (int c = 0; c < 8; ++c)
        a[c] = *(const half8*)&xT[16 * wave + l15][c * 32 + quad * 8];

    f32x4 acc[16];
    #pragma unroll
    for (int dt = 0; dt < 16; ++dt) acc[dt] = (f32x4){0.f, 0.f, 0.f, 0.f};

    const f16* Wb = Wt + (size_t)which * Dd * Dd;
    for (int c = 0; c < 8; ++c) {
        __syncthreads();
        #pragma unroll
        for (int jj = 0; jj < 4; ++jj) {
            int u = t + jj * 256, dp = u >> 2, p = u & 3;
            *(half8*)&Wls[dp][p * 8] =
                *(const half8*)(Wb + (size_t)dp * Dd + c * 32 + p * 8);
        }
        __syncthreads();
        #pragma unroll
        for (int dt = 0; dt < 16; ++dt) {
            half8 bfr = *(const half8*)&Wls[dt * 16 + l15][quad * 8];
            acc[dt] = __builtin_amdgcn_mfma_f32_16x16x32_f16(a[c], bfr, acc[dt], 0, 0, 0);
        }
    }

    const int nrow = n0 + 16 * wave + quad * 4;
    if (which < 2) {
        f16* O = (which == 0 ? Qh : Kh) + ((size_t)b * Nn + nrow) * Dd;
        #pragma unroll
        for (int dt = 0; dt < 16; ++dt) {
            int col = dt * 16 + l15;
            float bvv = bs[col];
            #pragma unroll
            for (int r = 0; r < 4; ++r)
                O[(size_t)r * Dd + col] = (f16)(acc[dt][r] + bvv);
        }
    } else {
        f16* O = Vth + (size_t)b * Dd * Nn;
        #pragma unroll
        for (int dt = 0; dt < 16; ++dt) {
            int col = dt * 16 + l15;
            float bvv = bs[col];
            half4 o;
            #pragma unroll
            for (int r = 0; r < 4; ++r) o[r] = (f16)(acc[dt][r] + bvv);
            *(half4*)&O[(size_t)col * Nn + nrow] = o;
        }
    }
}

// ---------------------------------------------------------------------------
// Kernel 2: MFMA flash attention. BQ=128, 512 threads (8 waves), split-KV,
// wave-split-D PV (32 d-cols/wave), pair-iteration V prefetch (full 128B
// line per d-row consumed immediately). Grid (N/128, B, SPLIT) = 512 blocks.
// ---------------------------------------------------------------------------
__global__ __launch_bounds__(512, 2) void attn_mfma(
    const f16* __restrict__ Qh, const f16* __restrict__ Kh,
    const f16* __restrict__ Vth, f16* __restrict__ Opart,
    float* __restrict__ mpart, float* __restrict__ lpart)
{
    __shared__ f16 Ks[BK][264];       // 16896 B  K[kv][d]
    __shared__ f16 Ps[8][16][36];     //  9216 B  P[qb][q][kv]
    __shared__ float alpha_s[8][16];  //   512 B
    __shared__ float l_sh[8][16];     //   512 B

    const int t    = threadIdx.x;
    const int wave = t >> 6, lane = t & 63;
    const int quad = lane >> 4, l15 = lane & 15;
    const int b    = blockIdx.y;
    const int s    = blockIdx.z;
    const int q0   = blockIdx.x * BQ;
    const int qw   = q0 + wave * 16;       // this wave's S-phase q rows
    const int kv0  = s * (Nn / SPLIT);

    // Q A-fragments, pre-scaled by log2(e)
    half8 qf[8];
    const f16* Qrow = Qh + ((size_t)b * Nn + qw + l15) * Dd + quad * 8;
    #pragma unroll
    for (int c = 0; c < 8; ++c) {
        qf[c] = *(const half8*)(Qrow + c * 32);
        qf[c] = qf[c] * (f16)LOG2E;
    }

    // acc[qb*2+dt]: q-block qb (0..7), d-cols 32*wave + dt*16 + l15 (dt 0..1)
    f32x4 acc[16];
    #pragma unroll
    for (int n = 0; n < 16; ++n) acc[n] = (f32x4){0.f, 0.f, 0.f, 0.f};
    f32x4 m4 = {-1e30f, -1e30f, -1e30f, -1e30f};
    f32x4 l4 = {0.f, 0.f, 0.f, 0.f};

    const f16* Kb   = Kh + (size_t)b * Nn * Dd;
    const f16* Vrow = Vth + (size_t)b * Dd * Nn
                    + (size_t)(wave * 32 + l15) * Nn + quad * 8;

    for (int k0p = kv0; k0p < kv0 + Nn / SPLIT; k0p += 2 * BK) {
        // Pair-top V prefetch: both sub-tiles, both d-tiles.
        // Per d-row the four 16B lane-reads + the +32 pair cover one full
        // 128B line, consumed this pair -> no L2-retention dependence.
        half8 vbf[2][2];   // [dt][sub]
        #pragma unroll
        for (int dt = 0; dt < 2; ++dt) {
            vbf[dt][0] = *(const half8*)(Vrow + (size_t)dt * 16 * Nn + k0p);
            vbf[dt][1] = *(const half8*)(Vrow + (size_t)dt * 16 * Nn + k0p + BK);
        }

        #pragma unroll
        for (int sub = 0; sub < 2; ++sub) {
            const int k0 = k0p + sub * BK;
            __syncthreads();   // prior readers of Ks/Ps done

            // Stage K tile: 32 rows x 512 B, 512 lanes x 16 B x 2
            #pragma unroll
            for (int i = 0; i < 2; ++i) {
                int u = t + i * 512;
                int r = u >> 5, c = u & 31;
                *(half8*)&Ks[r][c * 8] =
                    *(const half8*)(Kb + (size_t)(k0 + r) * Dd + c * 8);
            }
            __syncthreads();

            // S = Q K^T (log2 domain), two 16x16 col-blocks
            f32x4 S0 = {0.f, 0.f, 0.f, 0.f}, S1 = {0.f, 0.f, 0.f, 0.f};
            #pragma unroll
            for (int c = 0; c < 8; ++c) {
                half8 kb0 = *(const half8*)&Ks[l15][c * 32 + quad * 8];
                half8 kb1 = *(const half8*)&Ks[16 + l15][c * 32 + quad * 8];
                S0 = __builtin_amdgcn_mfma_f32_16x16x32_f16(qf[c], kb0, S0, 0, 0, 0);
                S1 = __builtin_amdgcn_mfma_f32_16x16x32_f16(qf[c], kb1, S1, 0, 0, 0);
            }

            // Online softmax (exp2 domain), DPP reductions
            f32x4 tmax;
            tmax.x = red16_max(fmaxf(S0.x, S1.x));
            tmax.y = red16_max(fmaxf(S0.y, S1.y));
            tmax.z = red16_max(fmaxf(S0.z, S1.z));
            tmax.w = red16_max(fmaxf(S0.w, S1.w));
            f32x4 newm;
            newm.x = fmaxf(m4.x, tmax.x); newm.y = fmaxf(m4.y, tmax.y);
            newm.z = fmaxf(m4.z, tmax.z); newm.w = fmaxf(m4.w, tmax.w);
            f32x4 al;
            al.x = __builtin_amdgcn_exp2f(m4.x - newm.x);
            al.y = __builtin_amdgcn_exp2f(m4.y - newm.y);
            al.z = __builtin_amdgcn_exp2f(m4.z - newm.z);
            al.w = __builtin_amdgcn_exp2f(m4.w - newm.w);
            f32x4 P0, P1;
            P0.x = __builtin_amdgcn_exp2f(S0.x - newm.x);
            P0.y = __builtin_amdgcn_exp2f(S0.y - newm.y);
            P0.z = __builtin_amdgcn_exp2f(S0.z - newm.z);
            P0.w = __builtin_amdgcn_exp2f(S0.w - newm.w);
            P1.x = __builtin_amdgcn_exp2f(S1.x - newm.x);
            P1.y = __builtin_amdgcn_exp2f(S1.y - newm.y);
            P1.z = __builtin_amdgcn_exp2f(S1.z - newm.z);
            P1.w = __builtin_amdgcn_exp2f(S1.w - newm.w);
            f32x4 rsum;
            rsum.x = red16_sum(P0.x + P1.x);
            rsum.y = red16_sum(P0.y + P1.y);
            rsum.z = red16_sum(P0.z + P1.z);
            rsum.w = red16_sum(P0.w + P1.w);
            l4 = l4 * al + rsum;
            m4 = newm;

            // Publish P (f16) and alpha
            const int pr = quad * 4;
            Ps[wave][pr + 0][l15] = (f16)P0.x;
            Ps[wave][pr + 1][l15] = (f16)P0.y;
            Ps[wave][pr + 2][l15] = (f16)P0.z;
            Ps[wave][pr + 3][l15] = (f16)P0.w;
            Ps[wave][pr + 0][16 + l15] = (f16)P1.x;
            Ps[wave][pr + 1][16 + l15] = (f16)P1.y;
            Ps[wave][pr + 2][16 + l15] = (f16)P1.z;
            Ps[wave][pr + 3][16 + l15] = (f16)P1.w;
            if (l15 == 0) {
                float4 a4 = {al.x, al.y, al.z, al.w};
                *(float4*)&alpha_s[wave][pr] = a4;
            }
            __syncthreads();

            // Rescale O by each q-block's alpha (skip when converged)
            float4 alq[8];
            int need = 0;
            #pragma unroll
            for (int qb = 0; qb < 8; ++qb) {
                alq[qb] = *(const float4*)&alpha_s[qb][pr];
                need |= (alq[qb].x != 1.f) | (alq[qb].y != 1.f) |
                        (alq[qb].z != 1.f) | (alq[qb].w != 1.f);
            }
            if (__any(need)) {
                #pragma unroll
                for (int qb = 0; qb < 8; ++qb) {
                    f32x4 a = {alq[qb].x, alq[qb].y, alq[qb].z, alq[qb].w};
                    acc[qb * 2 + 0] *= a;
                    acc[qb * 2 + 1] *= a;
                }
            }

            // PV: 8 q-blocks x this wave's 2 d-tiles
            #pragma unroll
            for (int qb = 0; qb < 8; ++qb) {
                half4 alo = *(const half4*)&Ps[qb][l15][quad * 8];
                half4 ahi = *(const half4*)&Ps[qb][l15][quad * 8 + 4];
                half8 ap = __builtin_shufflevector(alo, ahi, 0, 1, 2, 3, 4, 5, 6, 7);
                acc[qb * 2 + 0] = __builtin_amdgcn_mfma_f32_16x16x32_f16(
                    ap, vbf[0][sub], acc[qb * 2 + 0], 0, 0, 0);
                acc[qb * 2 + 1] = __builtin_amdgcn_mfma_f32_16x16x32_f16(
                    ap, vbf[1][sub], acc[qb * 2 + 1], 0, 0, 0);
            }
        }
    }

    // Publish l, write m/l partials (this wave's own 16 q rows)
    __syncthreads();
    if (l15 == 0) {
        const int pr = quad * 4;
        float4 lv = {l4.x, l4.y, l4.z, l4.w};
        *(float4*)&l_sh[wave][pr] = lv;
        float mv[4] = {m4.x, m4.y, m4.z, m4.w};
        float lvv[4] = {l4.x, l4.y, l4.z, l4.w};
        #pragma unroll
        for (int r = 0; r < 4; ++r) {
            int n = qw + pr + r;
            mpart[(size_t)(s * Bb + b) * Nn + n] = mv[r];
            lpart[(size_t)(s * Bb + b) * Nn + n] = lvv[r];
        }
    }
    __syncthreads();

    // Normalize + store partial O: 8 q-blocks x this wave's 2 d-tiles
    f16* Ob = Opart + (size_t)(s * Bb + b) * Dd * Nn;
    #pragma unroll
    for (int qb = 0; qb < 8; ++qb) {
        float4 lq = *(const float4*)&l_sh[qb][quad * 4];
        f32x4 inv = {1.f / lq.x, 1.f / lq.y, 1.f / lq.z, 1.f / lq.w};
        #pragma unroll
        for (int dt = 0; dt < 2; ++dt) {
            int d = wave * 32 + dt * 16 + l15;
            f32x4 o = acc[qb * 2 + dt] * inv;
            half4 oh;
            oh[0] = (f16)o.x; oh[1] = (f16)o.y; oh[2] = (f16)o.z; oh[3] = (f16)o.w;
            *(half4*)&Ob[(size_t)d * Nn + q0 + qb * 16 + quad * 4] = oh;
        }
    }
}

// ---------------------------------------------------------------------------
// Kernel 3: combine split partials (exp2 domain).
// ---------------------------------------------------------------------------
__global__ __launch_bounds__(256) void combine(
    const f16* __restrict__ Opart, const float* __restrict__ mpart,
    const float* __restrict__ lpart, float* __restrict__ out)
{
    const int t = threadIdx.x;
    const int n0 = (blockIdx.x * 256 + t) * 8;
    const int d = blockIdx.y, b = blockIdx.z;

    float m[SPLIT][8], l[SPLIT][8];
    #pragma unroll
    for (int s = 0; s < SPLIT; ++s) {
        size_t base = (size_t)(s * Bb + b) * Nn + n0;
        float4 a0 = *(const float4*)&mpart[base];
        float4 a1 = *(const float4*)&mpart[base + 4];
        float4 c0 = *(const float4*)&lpart[base];
        float4 c1 = *(const float4*)&lpart[base + 4];
        m[s][0]=a0.x; m[s][1]=a0.y; m[s][2]=a0.z; m[s][3]=a0.w;
        m[s][4]=a1.x; m[s][5]=a1.y; m[s][6]=a1.z; m[s][7]=a1.w;
        l[s][0]=c0.x; l[s][1]=c0.y; l[s][2]=c0.z; l[s][3]=c0.w;
        l[s][4]=c1.x; l[s][5]=c1.y; l[s][6]=c1.z; l[s][7]=c1.w;
    }
    float w[SPLIT][8];
    #pragma unroll
    for (int jx = 0; jx < 8; ++jx) {
        float M = m[0][jx];
        #pragma unroll
        for (int s = 1; s < SPLIT; ++s) M = fmaxf(M, m[s][jx]);
        float L = 0.f;
        #pragma unroll
        for (int s = 0; s < SPLIT; ++s) {
            float ws = l[s][jx] * __builtin_amdgcn_exp2f(m[s][jx] - M);
            w[s][jx] = ws; L += ws;
        }
        float invL = 1.f / L;
        #pragma unroll
        for (int s = 0; s < SPLIT; ++s) w[s][jx] *= invL;
    }

    float o[8];
    #pragma unroll
    for (int jx = 0; jx < 8; ++jx) o[jx] = 0.f;
    #pragma unroll
    for (int s = 0; s < SPLIT; ++s) {
        half8 h = *(const half8*)&Opart[((size_t)(s * Bb + b) * Dd + d) * Nn + n0];
        #pragma unroll
        for (int jx = 0; jx < 8; ++jx) o[jx] += w[s][jx] * (float)h[jx];
    }
    float* op = out + ((size_t)b * Dd + d) * Nn + n0;
    f32x4 o0 = {o[0], o[1], o[2], o[3]};
    f32x4 o1 = {o[4], o[5], o[6], o[7]};
    *(f32x4*)op = o0;
    *(f32x4*)(op + 4) = o1;
}

extern "C" void kernel_launch(void* const* d_in, const int* in_sizes, int n_in,
                              void* d_out, int out_size, void* d_ws, size_t ws_size,
                              hipStream_t stream) {
    const float* x  = (const float*)d_in[0];
    const float* Wq = (const float*)d_in[1];
    const float* bq = (const float*)d_in[2];
    const float* Wk = (const float*)d_in[3];
    const float* bk = (const float*)d_in[4];
    const float* Wv = (const float*)d_in[5];
    const float* bv = (const float*)d_in[6];
    float* out = (float*)d_out;

    f16* Qh    = (f16*)d_ws;
    f16* Kh    = Qh + (size_t)Bb * Nn * Dd;
    f16* Vth   = Kh + (size_t)Bb * Nn * Dd;
    f16* Wt    = Vth + (size_t)Bb * Nn * Dd;
    f16* Opart = Wt + (size_t)3 * Dd * Dd;
    float* mpart = (float*)(Opart + (size_t)SPLIT * Bb * Dd * Nn);
    float* lpart = mpart + (size_t)SPLIT * Bb * Nn;

    wtrans<<<dim3(16, 3), 256, 0, stream>>>(Wq, Wk, Wv, Wt);
    qkv_mfma<<<dim3(Nn / 64, Bb, 3), 256, 0, stream>>>(
        x, Wt, bq, bk, bv, Qh, Kh, Vth);
    attn_mfma<<<dim3(Nn / BQ, Bb, SPLIT), 512, 0, stream>>>(
        Qh, Kh, Vth, Opart, mpart, lpart);
    combine<<<dim3(Nn / 2048, Dd, Bb), 256, 0, stream>>>(
        Opart, mpart, lpart, out);
}